// Round 3
// baseline (30.696 us; speedup 1.0000x reference)
//
#include <hip/hip_runtime.h>

#define B_ 8
#define S_ 1024
#define D_ 2048
#define E_ 2
#define NROWS (E_ * D_ + E_)   // 4098 reduction rows (W rows + bias rows)

typedef float f32x4 __attribute__((ext_vector_type(4)));  // builtin-compatible float4

// ---------- wave-level reduction helpers (wave64, no LDS) ----------
__device__ inline float wave_reduce_sum(float v) {
    #pragma unroll
    for (int off = 32; off > 0; off >>= 1) v += __shfl_down(v, off, 64);
    return v;
}
__device__ inline float wave_reduce_max(float v) {
    #pragma unroll
    for (int off = 32; off > 0; off >>= 1) v = fmaxf(v, __shfl_down(v, off, 64));
    return v;
}

// ---------- kernel 1: Wsum[e,d] = sum_h W[e,d,h]; bsum[e] = sum_h b[e,h] ----------
// One WAVE per row (D=2048 floats = 8 f32x4/lane). 4 waves/block, no barriers.
__global__ __launch_bounds__(256) void reduce_rows_kernel(
        const float* __restrict__ W, const float* __restrict__ bvec,
        float* __restrict__ Wsum, float* __restrict__ bsum) {
    const int wave = threadIdx.x >> 6, lane = threadIdx.x & 63;
    const int row = blockIdx.x * 4 + wave;
    if (row >= NROWS) return;
    const float* src = (row < E_ * D_) ? (W + (size_t)row * D_)
                                       : (bvec + (size_t)(row - E_ * D_) * D_);
    const f32x4* s4 = (const f32x4*)src;
    float s = 0.0f;
    #pragma unroll
    for (int j = 0; j < D_ / 4 / 64; ++j) {
        f32x4 v = __builtin_nontemporal_load(&s4[lane + j * 64]);  // W streamed once
        s += (v.x + v.y) + (v.z + v.w);
    }
    s = wave_reduce_sum(s);
    if (lane == 0) {
        if (row < E_ * D_) Wsum[row] = s;
        else               bsum[row - E_ * D_] = s;
    }
}

// ---------- kernel 2: per-token gate + selected-expert row-sum ----------
// One WAVE per token: y[tok] = gate * (dot(x, Wsum[idx]) + bsum[idx])
__global__ __launch_bounds__(256) void token_kernel(
        const float* __restrict__ x, const float* __restrict__ wg,
        const float* __restrict__ Wsum, const float* __restrict__ bsum,
        float* __restrict__ y) {
    const int wave = threadIdx.x >> 6, lane = threadIdx.x & 63;
    const int tok = blockIdx.x * 4 + wave;
    const f32x4* x4  = (const f32x4*)(x + (size_t)tok * D_);
    const f32x4* w0  = (const f32x4*)(Wsum);
    const f32x4* w1  = (const f32x4*)(Wsum + D_);
    const f32x4* wg4 = (const f32x4*)(wg);   // wg is [D,E=2] interleaved

    float d0 = 0.0f, d1 = 0.0f, g0 = 0.0f, g1 = 0.0f;
    #pragma unroll
    for (int j = 0; j < D_ / 4 / 64; ++j) {
        const int i = lane + j * 64;                       // coalesced across lanes
        f32x4 xv = __builtin_nontemporal_load(&x4[i]);     // x streamed once
        f32x4 a  = w0[i];                                  // L1/L2-resident
        f32x4 c  = w1[i];
        f32x4 u  = wg4[2 * i];
        f32x4 v  = wg4[2 * i + 1];
        d0 += xv.x * a.x + xv.y * a.y + xv.z * a.z + xv.w * a.w;
        d1 += xv.x * c.x + xv.y * c.y + xv.z * c.z + xv.w * c.w;
        g0 += xv.x * u.x + xv.y * u.z + xv.z * v.x + xv.w * v.z;
        g1 += xv.x * u.y + xv.y * u.w + xv.z * v.y + xv.w * v.w;
    }
    d0 = wave_reduce_sum(d0);
    d1 = wave_reduce_sum(d1);
    g0 = wave_reduce_sum(g0);
    g1 = wave_reduce_sum(g1);

    if (lane == 0) {
        // jnp.argmax: first occurrence of max -> idx=1 only on strict g1 > g0
        const int idx = (g1 > g0) ? 1 : 0;
        const float diff = idx ? (g0 - g1) : (g1 - g0);    // l_other - l_chosen, <= 0
        const float gate = 1.0f / (1.0f + expf(diff));
        const float dot  = idx ? d1 : d0;
        y[tok] = gate * (dot + bsum[idx]);
    }
}

// ---------- kernel 3: log_softmax over axis=1 (S) ----------
// One block per batch row; row held in registers (256 threads x f32x4).
__global__ __launch_bounds__(256) void logsoftmax_kernel(
        const float* __restrict__ y, float* __restrict__ out) {
    const int b = blockIdx.x;
    const f32x4* row4 = (const f32x4*)(y + (size_t)b * S_);
    f32x4 v = row4[threadIdx.x];

    float m = fmaxf(fmaxf(v.x, v.y), fmaxf(v.z, v.w));
    m = wave_reduce_max(m);
    __shared__ float lds[4];
    __shared__ float M_s, L_s;
    const int wave = threadIdx.x >> 6, lane = threadIdx.x & 63;
    if (lane == 0) lds[wave] = m;
    __syncthreads();
    if (threadIdx.x == 0)
        M_s = fmaxf(fmaxf(lds[0], lds[1]), fmaxf(lds[2], lds[3]));
    __syncthreads();
    const float M = M_s;

    float s = expf(v.x - M) + expf(v.y - M) + expf(v.z - M) + expf(v.w - M);
    s = wave_reduce_sum(s);
    __syncthreads();
    if (lane == 0) lds[wave] = s;
    __syncthreads();
    if (threadIdx.x == 0)
        L_s = M + logf(lds[0] + lds[1] + lds[2] + lds[3]);
    __syncthreads();
    const float lse = L_s;

    f32x4 o;
    o.x = v.x - lse; o.y = v.y - lse; o.z = v.z - lse; o.w = v.w - lse;
    ((f32x4*)(out + (size_t)b * S_))[threadIdx.x] = o;
}

extern "C" void kernel_launch(void* const* d_in, const int* in_sizes, int n_in,
                              void* d_out, int out_size, void* d_ws, size_t ws_size,
                              hipStream_t stream) {
    const float* x  = (const float*)d_in[0];   // [B,S,D]
    const float* wg = (const float*)d_in[1];   // [D,E]
    const float* W  = (const float*)d_in[2];   // [E,D,D]
    const float* bv = (const float*)d_in[3];   // [E,D]
    float* out = (float*)d_out;                // [B,S]

    float* ws   = (float*)d_ws;
    float* Wsum = ws;                  // E*D = 4096 floats
    float* bsum = ws + E_ * D_;        // 2 floats
    float* y    = ws + E_ * D_ + 16;   // B*S = 8192 floats (16B-aligned offset)

    reduce_rows_kernel<<<(NROWS + 3) / 4, 256, 0, stream>>>(W, bv, Wsum, bsum);
    token_kernel<<<B_ * S_ / 4, 256, 0, stream>>>(x, wg, Wsum, bsum, y);
    logsoftmax_kernel<<<B_, 256, 0, stream>>>(y, out);
}

// Round 4
// 25.733 us; speedup vs baseline: 1.1929x; 1.1929x over previous
//
#include <hip/hip_runtime.h>

#define B_ 8
#define S_ 1024
#define D_ 2048
#define E_ 2
#define NROWS (E_ * D_ + E_)   // 4098 reduction rows (W rows + bias rows)

typedef float f32x4 __attribute__((ext_vector_type(4)));

// ---------- wave-level reduction helpers (wave64, no LDS) ----------
__device__ inline float wave_reduce_sum(float v) {
    #pragma unroll
    for (int off = 32; off > 0; off >>= 1) v += __shfl_down(v, off, 64);
    return v;
}
__device__ inline float wave_reduce_max(float v) {
    #pragma unroll
    for (int off = 32; off > 0; off >>= 1) v = fmaxf(v, __shfl_down(v, off, 64));
    return v;
}

// ---------- kernel 1: Wsum[e,d] = sum_h W[e,d,h]; bsum[e] = sum_h b[e,h] ----------
// One WAVE per row (D=2048 floats = 8 f32x4/lane). 4 waves/block, no barriers.
__global__ __launch_bounds__(256) void reduce_rows_kernel(
        const float* __restrict__ W, const float* __restrict__ bvec,
        float* __restrict__ Wsum, float* __restrict__ bsum) {
    const int wave = threadIdx.x >> 6, lane = threadIdx.x & 63;
    const int row = blockIdx.x * 4 + wave;
    if (row >= NROWS) return;
    const float* src = (row < E_ * D_) ? (W + (size_t)row * D_)
                                       : (bvec + (size_t)(row - E_ * D_) * D_);
    const f32x4* s4 = (const f32x4*)src;
    float s = 0.0f;
    #pragma unroll
    for (int j = 0; j < D_ / 4 / 64; ++j) {
        f32x4 v = __builtin_nontemporal_load(&s4[lane + j * 64]);  // W streamed once
        s += (v.x + v.y) + (v.z + v.w);
    }
    s = wave_reduce_sum(s);
    if (lane == 0) {
        if (row < E_ * D_) Wsum[row] = s;
        else               bsum[row - E_ * D_] = s;
    }
}

// ---------- kernel 2: per-token gate + selected-expert row-sum ----------
// Weights staged in LDS once per block (32 KB); 2 tokens per wave share each
// weight read. Grid = B*S/8 blocks of 4 waves.
__global__ __launch_bounds__(256) void token_kernel(
        const float* __restrict__ x, const float* __restrict__ wg,
        const float* __restrict__ Wsum, const float* __restrict__ bsum,
        float* __restrict__ y) {
    __shared__ float lw0[D_], lw1[D_], lg0[D_], lg1[D_];   // 32 KB
    const int tid = threadIdx.x;

    // ---- stage: Wsum rows + de-interleaved wg columns ----
    {
        const f32x4* w0g = (const f32x4*)(Wsum);
        const f32x4* w1g = (const f32x4*)(Wsum + D_);
        const f32x4* wgg = (const f32x4*)(wg);            // [D,2] interleaved
        f32x4* l0 = (f32x4*)lw0; f32x4* l1 = (f32x4*)lw1;
        f32x4* g0 = (f32x4*)lg0; f32x4* g1 = (f32x4*)lg1;
        #pragma unroll
        for (int i = tid; i < D_ / 4; i += 256) {
            l0[i] = w0g[i];
            l1[i] = w1g[i];
            f32x4 u = wgg[2 * i];                         // d=4i..4i+1 pairs
            f32x4 v = wgg[2 * i + 1];                     // d=4i+2..4i+3 pairs
            f32x4 a, b;
            a.x = u.x; a.y = u.z; a.z = v.x; a.w = v.z;   // expert-0 gate col
            b.x = u.y; b.y = u.w; b.z = v.y; b.w = v.w;   // expert-1 gate col
            g0[i] = a;
            g1[i] = b;
        }
    }
    __syncthreads();

    const int wave = tid >> 6, lane = tid & 63;
    const int t0 = blockIdx.x * 8 + wave * 2;             // 2 tokens per wave
    const int t1 = t0 + 1;
    const f32x4* xa = (const f32x4*)(x + (size_t)t0 * D_);
    const f32x4* xb = (const f32x4*)(x + (size_t)t1 * D_);
    const f32x4* l0 = (const f32x4*)lw0;
    const f32x4* l1 = (const f32x4*)lw1;
    const f32x4* c0 = (const f32x4*)lg0;
    const f32x4* c1 = (const f32x4*)lg1;

    float d0a = 0, d1a = 0, g0a = 0, g1a = 0;
    float d0b = 0, d1b = 0, g0b = 0, g1b = 0;
    #pragma unroll
    for (int j = 0; j < D_ / 4 / 64; ++j) {
        const int i = lane + j * 64;
        f32x4 x0 = __builtin_nontemporal_load(&xa[i]);    // x streamed once
        f32x4 x1 = __builtin_nontemporal_load(&xb[i]);
        f32x4 a = l0[i], c = l1[i], u = c0[i], v = c1[i];
        d0a += x0.x * a.x + x0.y * a.y + x0.z * a.z + x0.w * a.w;
        d1a += x0.x * c.x + x0.y * c.y + x0.z * c.z + x0.w * c.w;
        g0a += x0.x * u.x + x0.y * u.y + x0.z * u.z + x0.w * u.w;
        g1a += x0.x * v.x + x0.y * v.y + x0.z * v.z + x0.w * v.w;
        d0b += x1.x * a.x + x1.y * a.y + x1.z * a.z + x1.w * a.w;
        d1b += x1.x * c.x + x1.y * c.y + x1.z * c.z + x1.w * c.w;
        g0b += x1.x * u.x + x1.y * u.y + x1.z * u.z + x1.w * u.w;
        g1b += x1.x * v.x + x1.y * v.y + x1.z * v.z + x1.w * v.w;
    }
    d0a = wave_reduce_sum(d0a); d1a = wave_reduce_sum(d1a);
    g0a = wave_reduce_sum(g0a); g1a = wave_reduce_sum(g1a);
    d0b = wave_reduce_sum(d0b); d1b = wave_reduce_sum(d1b);
    g0b = wave_reduce_sum(g0b); g1b = wave_reduce_sum(g1b);

    if (lane == 0) {
        // jnp.argmax: first occurrence of max -> idx=1 only on strict g1 > g0
        {
            const int idx = (g1a > g0a) ? 1 : 0;
            const float diff = idx ? (g0a - g1a) : (g1a - g0a);  // <= 0
            const float gate = 1.0f / (1.0f + expf(diff));
            y[t0] = gate * ((idx ? d1a : d0a) + bsum[idx]);
        }
        {
            const int idx = (g1b > g0b) ? 1 : 0;
            const float diff = idx ? (g0b - g1b) : (g1b - g0b);
            const float gate = 1.0f / (1.0f + expf(diff));
            y[t1] = gate * ((idx ? d1b : d0b) + bsum[idx]);
        }
    }
}

// ---------- kernel 3: log_softmax over axis=1 (S) ----------
// One block per batch row; row held in registers (256 threads x f32x4).
__global__ __launch_bounds__(256) void logsoftmax_kernel(
        const float* __restrict__ y, float* __restrict__ out) {
    const int b = blockIdx.x;
    const f32x4* row4 = (const f32x4*)(y + (size_t)b * S_);
    f32x4 v = row4[threadIdx.x];

    float m = fmaxf(fmaxf(v.x, v.y), fmaxf(v.z, v.w));
    m = wave_reduce_max(m);
    __shared__ float lds[4];
    __shared__ float M_s, L_s;
    const int wave = threadIdx.x >> 6, lane = threadIdx.x & 63;
    if (lane == 0) lds[wave] = m;
    __syncthreads();
    if (threadIdx.x == 0)
        M_s = fmaxf(fmaxf(lds[0], lds[1]), fmaxf(lds[2], lds[3]));
    __syncthreads();
    const float M = M_s;

    float s = expf(v.x - M) + expf(v.y - M) + expf(v.z - M) + expf(v.w - M);
    s = wave_reduce_sum(s);
    __syncthreads();
    if (lane == 0) lds[wave] = s;
    __syncthreads();
    if (threadIdx.x == 0)
        L_s = M + logf(lds[0] + lds[1] + lds[2] + lds[3]);
    __syncthreads();
    const float lse = L_s;

    f32x4 o;
    o.x = v.x - lse; o.y = v.y - lse; o.z = v.z - lse; o.w = v.w - lse;
    ((f32x4*)(out + (size_t)b * S_))[threadIdx.x] = o;
}

extern "C" void kernel_launch(void* const* d_in, const int* in_sizes, int n_in,
                              void* d_out, int out_size, void* d_ws, size_t ws_size,
                              hipStream_t stream) {
    const float* x  = (const float*)d_in[0];   // [B,S,D]
    const float* wg = (const float*)d_in[1];   // [D,E]
    const float* W  = (const float*)d_in[2];   // [E,D,D]
    const float* bv = (const float*)d_in[3];   // [E,D]
    float* out = (float*)d_out;                // [B,S]

    float* ws   = (float*)d_ws;
    float* Wsum = ws;                  // E*D = 4096 floats
    float* bsum = ws + E_ * D_;        // 2 floats
    float* y    = ws + E_ * D_ + 16;   // B*S = 8192 floats (16B-aligned offset)

    reduce_rows_kernel<<<(NROWS + 3) / 4, 256, 0, stream>>>(W, bv, Wsum, bsum);
    token_kernel<<<B_ * S_ / 8, 256, 0, stream>>>(x, wg, Wsum, bsum, y);
    logsoftmax_kernel<<<B_, 256, 0, stream>>>(y, out);
}